// Round 1
// baseline (257.379 us; speedup 1.0000x reference)
//
#include <hip/hip_runtime.h>

// ExampleModelSISO: out = x * exclusive_cumsum(x, axis=time)
// x: [B=8, T=4096, D=1024] float32, out same shape.
// 3-kernel chunked scan over the time axis.

constexpr int B = 8;
constexpr int T = 4096;
constexpr int D = 1024;
constexpr int C = 64;        // chunks along T
constexpr int L = T / C;     // 64 timesteps per chunk
constexpr int THREADS = 256; // 256 threads * float4 = 1024 = D

// Kernel 1: per-chunk sums. Block = one (b, chunk); thread = 4 consecutive d.
__global__ __launch_bounds__(THREADS)
void partial_sums(const float* __restrict__ x, float* __restrict__ part) {
    const int bc = blockIdx.x;
    const int b = bc / C;
    const int c = bc % C;
    const int d4 = threadIdx.x * 4;

    const float* px = x + ((size_t)(b * T + c * L)) * D + d4;
    float4 acc = make_float4(0.f, 0.f, 0.f, 0.f);
#pragma unroll 8
    for (int t = 0; t < L; ++t) {
        float4 v = *(const float4*)(px + (size_t)t * D);
        acc.x += v.x; acc.y += v.y; acc.z += v.z; acc.w += v.w;
    }
    // layout: part[c][b][d]
    *(float4*)(part + ((size_t)c * B + b) * D + d4) = acc;
}

// Kernel 2: exclusive scan of the C chunk sums for each (b,d) chain, in place.
// One thread per 4 d's of one (b,d4) chain: B*D/4 = 2048 threads.
__global__ __launch_bounds__(THREADS)
void scan_partials(float* __restrict__ part) {
    const int j = blockIdx.x * blockDim.x + threadIdx.x; // 0 .. B*D/4-1
    const int bd4 = j * 4;
    float4 run = make_float4(0.f, 0.f, 0.f, 0.f);
#pragma unroll 4
    for (int c = 0; c < C; ++c) {
        float4* p = (float4*)(part + (size_t)c * (B * D) + bd4);
        float4 v = *p;
        *p = run;
        run.x += v.x; run.y += v.y; run.z += v.z; run.w += v.w;
    }
}

// Kernel 3: within-chunk exclusive scan seeded by chunk prefix; out = x * s_prev.
__global__ __launch_bounds__(THREADS)
void scan_mul(const float* __restrict__ x, const float* __restrict__ part,
              float* __restrict__ out) {
    const int bc = blockIdx.x;
    const int b = bc / C;
    const int c = bc % C;
    const int d4 = threadIdx.x * 4;

    const size_t base = ((size_t)(b * T + c * L)) * D + d4;
    float4 s = *(const float4*)(part + ((size_t)c * B + b) * D + d4);
#pragma unroll 4
    for (int t = 0; t < L; ++t) {
        float4 v = *(const float4*)(x + base + (size_t)t * D);
        float4 o;
        o.x = v.x * s.x; o.y = v.y * s.y; o.z = v.z * s.z; o.w = v.w * s.w;
        s.x += v.x; s.y += v.y; s.z += v.z; s.w += v.w;
        *(float4*)(out + base + (size_t)t * D) = o;
    }
}

extern "C" void kernel_launch(void* const* d_in, const int* in_sizes, int n_in,
                              void* d_out, int out_size, void* d_ws, size_t ws_size,
                              hipStream_t stream) {
    const float* x = (const float*)d_in[0];
    float* out = (float*)d_out;
    float* part = (float*)d_ws; // needs C*B*D*4 = 2 MiB of scratch

    partial_sums<<<B * C, THREADS, 0, stream>>>(x, part);
    scan_partials<<<(B * D / 4) / THREADS, THREADS, 0, stream>>>(part);
    scan_mul<<<B * C, THREADS, 0, stream>>>(x, part, out);
}

// Round 3
// 254.017 us; speedup vs baseline: 1.0132x; 1.0132x over previous
//
#include <hip/hip_runtime.h>

// ExampleModelSISO: out = x * exclusive_cumsum(x, axis=time)
// x: [B=8, T=4096, D=1024] float32, out same shape.
// 3-kernel chunked scan over the time axis.
// R3: fix nontemporal-store type (ext_vector_type float4, not HIP float4).
// C=128 (1024 blocks for k1/k3), k2 8192-thread coalesced register-tiled
// scan, nontemporal out-stores in k3 to keep x resident in L2/L3.

typedef float vf4 __attribute__((ext_vector_type(4)));

constexpr int B = 8;
constexpr int T = 4096;
constexpr int D = 1024;
constexpr int C = 128;       // chunks along T
constexpr int L = T / C;     // 32 timesteps per chunk
constexpr int THREADS = 256; // 256 threads * float4 = 1024 = D
constexpr int BD = B * D;    // 8192 chains

// Kernel 1: per-chunk sums. Block = one (b, chunk); thread = 4 consecutive d.
// part layout: part[c][b*D + d]  (chain index = b*D+d)
__global__ __launch_bounds__(THREADS)
void partial_sums(const float* __restrict__ x, float* __restrict__ part) {
    const int bc = blockIdx.x;
    const int b = bc / C;
    const int c = bc % C;
    const int d4 = threadIdx.x * 4;

    const float* px = x + ((size_t)(b * T + c * L)) * D + d4;
    vf4 acc = (vf4)(0.f);
#pragma unroll 8
    for (int t = 0; t < L; ++t) {
        vf4 v = *(const vf4*)(px + (size_t)t * D);
        acc += v;
    }
    *(vf4*)(part + (size_t)c * BD + b * D + d4) = acc;
}

// Kernel 2: exclusive scan of the C chunk sums along c for each chain.
// One thread per chain (8192 threads). Loads are coalesced across lanes.
// Register tiles of 16 so 16 loads are in flight before the serial scan.
__global__ __launch_bounds__(THREADS)
void scan_partials(float* __restrict__ part) {
    const int j = blockIdx.x * blockDim.x + threadIdx.x; // chain id, 0..BD-1
    float run = 0.f;
    constexpr int TILE = 16;
#pragma unroll
    for (int c0 = 0; c0 < C; c0 += TILE) {
        float v[TILE];
#pragma unroll
        for (int k = 0; k < TILE; ++k)
            v[k] = part[(size_t)(c0 + k) * BD + j];
#pragma unroll
        for (int k = 0; k < TILE; ++k) {
            part[(size_t)(c0 + k) * BD + j] = run;
            run += v[k];
        }
    }
}

// Kernel 3: within-chunk exclusive scan seeded by chunk prefix; out = x * s_prev.
__global__ __launch_bounds__(THREADS)
void scan_mul(const float* __restrict__ x, const float* __restrict__ part,
              float* __restrict__ out) {
    const int bc = blockIdx.x;
    const int b = bc / C;
    const int c = bc % C;
    const int d4 = threadIdx.x * 4;

    const size_t base = ((size_t)(b * T + c * L)) * D + d4;
    vf4 s = *(const vf4*)(part + (size_t)c * BD + b * D + d4);
#pragma unroll 4
    for (int t = 0; t < L; ++t) {
        vf4 v = *(const vf4*)(x + base + (size_t)t * D);
        vf4 o = v * s;
        s += v;
        __builtin_nontemporal_store(o, (vf4*)(out + base + (size_t)t * D));
    }
}

extern "C" void kernel_launch(void* const* d_in, const int* in_sizes, int n_in,
                              void* d_out, int out_size, void* d_ws, size_t ws_size,
                              hipStream_t stream) {
    const float* x = (const float*)d_in[0];
    float* out = (float*)d_out;
    float* part = (float*)d_ws; // C*B*D*4 = 4 MiB of scratch

    partial_sums<<<B * C, THREADS, 0, stream>>>(x, part);
    scan_partials<<<BD / THREADS, THREADS, 0, stream>>>(part);
    scan_mul<<<B * C, THREADS, 0, stream>>>(x, part, out);
}